// Round 6
// baseline (307.545 us; speedup 1.0000x reference)
//
#include <hip/hip_runtime.h>

#define D 256

typedef unsigned short ushort_t;
typedef unsigned int uint_t;
typedef __attribute__((ext_vector_type(8))) short short8;
typedef __attribute__((ext_vector_type(4))) float floatx4;

static __device__ __forceinline__ ushort_t f2bf(float f) {
    union { float f; uint_t u; } c; c.f = f;
    uint_t r = (c.u + 0x7FFFu + ((c.u >> 16) & 1u)) >> 16;   // RN-even
    return (ushort_t)r;
}
static __device__ __forceinline__ float bf2f(ushort_t b) {
    union { uint_t u; float f; } c; c.u = ((uint_t)b) << 16;
    return c.f;
}

// ---------------------------------------------------------------------------
// Fused prep, 3 grid sections:
//  [0,degB):      rank[e] = atomicAdd(&deg[col[e]],1)  (histogram + edge rank)
//  [degB,+cvtB):  x -> bf16 (xh)
//  rest:          BT[j][k] j-major: k<256 Wself[k][j] | k<512 Wsrc | k<768 Wdst
// ---------------------------------------------------------------------------
__global__ void prep_kernel(const int* __restrict__ col, int* __restrict__ deg,
                            int* __restrict__ rank,
                            const float* __restrict__ x, ushort_t* __restrict__ xh,
                            const float* __restrict__ Wself, const float* __restrict__ Wsrc,
                            const float* __restrict__ Wdst, ushort_t* __restrict__ BT,
                            int E, int total8, int degB, int cvtB) {
    int b = blockIdx.x;
    if (b < degB) {
        int e = b * 256 + threadIdx.x;
        if (e < E) rank[e] = atomicAdd(&deg[col[e]], 1);
    } else if (b < degB + cvtB) {
        int i = (b - degB) * 256 + threadIdx.x;
        if (i >= total8) return;
        float4 a = ((const float4*)x)[i * 2];
        float4 bb = ((const float4*)x)[i * 2 + 1];
        uint4 o;
        o.x = f2bf(a.x) | ((uint_t)f2bf(a.y) << 16);
        o.y = f2bf(a.z) | ((uint_t)f2bf(a.w) << 16);
        o.z = f2bf(bb.x) | ((uint_t)f2bf(bb.y) << 16);
        o.w = f2bf(bb.z) | ((uint_t)f2bf(bb.w) << 16);
        ((uint4*)xh)[i] = o;
    } else {
        int id = (b - degB - cvtB) * 256 + threadIdx.x;   // j*768+k
        if (id >= 256 * 768) return;
        int j = id / 768, k = id % 768;
        float v;
        if (k < 256)      v = Wself[(size_t)k * 256 + j];
        else if (k < 512) v = Wsrc [(size_t)(k - 256) * 256 + j];
        else              v = Wdst [(size_t)(k - 512) * 256 + j];
        BT[id] = f2bf(v);
    }
}

// ---------------------------------------------------------------------------
// Scan phase A: per-block (1024 elems) local exclusive scan into off,
// block totals into partials. 256 threads x int4.
// ---------------------------------------------------------------------------
__global__ __launch_bounds__(256) void scanA(const int* __restrict__ deg,
                                             int* __restrict__ off,
                                             int* __restrict__ partials, int n4) {
    __shared__ int wtot[4];
    const int tid = threadIdx.x, lane = tid & 63, wid = tid >> 6;
    int i4 = blockIdx.x * 256 + tid;
    int4 v = (i4 < n4) ? ((const int4*)deg)[i4] : make_int4(0, 0, 0, 0);
    int s = v.x + v.y + v.z + v.w;
    int incl = s;
    #pragma unroll
    for (int st = 1; st < 64; st <<= 1) {
        int t = __shfl_up(incl, st, 64);
        if (lane >= st) incl += t;
    }
    if (lane == 63) wtot[wid] = incl;
    __syncthreads();
    int wbase = 0;
    #pragma unroll
    for (int w = 0; w < 4; ++w) if (w < wid) wbase += wtot[w];
    int excl = incl - s + wbase;
    if (i4 < n4) {
        int4 o;
        o.x = excl; o.y = o.x + v.x; o.z = o.y + v.y; o.w = o.z + v.z;
        ((int4*)off)[i4] = o;
    }
    if (tid == 0) partials[blockIdx.x] = wtot[0] + wtot[1] + wtot[2] + wtot[3];
}

// ---------------------------------------------------------------------------
// Scan phase C: add exclusive block base (sum of earlier partials, <=64 blocks).
// ---------------------------------------------------------------------------
__global__ __launch_bounds__(256) void scanC(int* __restrict__ off,
                                             const int* __restrict__ partials, int n4) {
    __shared__ int base_s;
    const int tid = threadIdx.x;
    if (tid < 64) {
        int v = (tid < blockIdx.x) ? partials[tid] : 0;
        #pragma unroll
        for (int st = 32; st; st >>= 1) v += __shfl_down(v, st, 64);
        if (tid == 0) base_s = v;
    }
    __syncthreads();
    int base = base_s;
    int i4 = blockIdx.x * 256 + tid;
    if (i4 < n4) {
        int4 o = ((int4*)off)[i4];
        o.x += base; o.y += base; o.z += base; o.w += base;
        ((int4*)off)[i4] = o;
    }
}

// ---------------------------------------------------------------------------
// Atomic-free bucket fill using precomputed ranks.
// ---------------------------------------------------------------------------
__global__ void fill_kernel(const int* __restrict__ row, const int* __restrict__ col,
                            const int* __restrict__ rank, const int* __restrict__ off,
                            int* __restrict__ bucket, int E) {
    int e = blockIdx.x * blockDim.x + threadIdx.x;
    if (e >= E) return;
    bucket[off[col[e]] + rank[e]] = row[e];
}

// ---------------------------------------------------------------------------
// Per-node gather-sum over bf16 rows, fp32 accum, bf16 out. One wave/node,
// lane = 4 consecutive bf16 (8B). 4-wide unroll for MLP.
// ---------------------------------------------------------------------------
__global__ __launch_bounds__(256) void segsum_kernel(const ushort_t* __restrict__ xh,
                                                     const int* __restrict__ off,
                                                     const int* __restrict__ deg,
                                                     const int* __restrict__ bucket,
                                                     ushort_t* __restrict__ Gh, int N) {
    int node = blockIdx.x * 4 + (threadIdx.x >> 6);
    int lane = threadIdx.x & 63;
    if (node >= N) return;
    int start = off[node];
    int cnt = deg[node];
    float a0 = 0.f, a1 = 0.f, a2 = 0.f, a3 = 0.f;
    int i = 0;
    for (; i + 4 <= cnt; i += 4) {
        int r0 = bucket[start + i];
        int r1 = bucket[start + i + 1];
        int r2 = bucket[start + i + 2];
        int r3 = bucket[start + i + 3];
        ushort4 v0 = ((const ushort4*)(xh + (size_t)r0 * D))[lane];
        ushort4 v1 = ((const ushort4*)(xh + (size_t)r1 * D))[lane];
        ushort4 v2 = ((const ushort4*)(xh + (size_t)r2 * D))[lane];
        ushort4 v3 = ((const ushort4*)(xh + (size_t)r3 * D))[lane];
        a0 += (bf2f(v0.x) + bf2f(v1.x)) + (bf2f(v2.x) + bf2f(v3.x));
        a1 += (bf2f(v0.y) + bf2f(v1.y)) + (bf2f(v2.y) + bf2f(v3.y));
        a2 += (bf2f(v0.z) + bf2f(v1.z)) + (bf2f(v2.z) + bf2f(v3.z));
        a3 += (bf2f(v0.w) + bf2f(v1.w)) + (bf2f(v2.w) + bf2f(v3.w));
    }
    for (; i < cnt; ++i) {
        int r0 = bucket[start + i];
        ushort4 v0 = ((const ushort4*)(xh + (size_t)r0 * D))[lane];
        a0 += bf2f(v0.x); a1 += bf2f(v0.y); a2 += bf2f(v0.z); a3 += bf2f(v0.w);
    }
    ushort4 o;
    o.x = f2bf(a0); o.y = f2bf(a1); o.z = f2bf(a2); o.w = f2bf(a3);
    ((ushort4*)(Gh + (size_t)node * D))[lane] = o;
}

// ---------------------------------------------------------------------------
// bf16 MFMA GEMM v6: ZERO-LDS, ZERO-BARRIER register-direct kernel.
//
// Insight (rounds 0/2/4/5 post-mortem): four different staging schedules all
// pinned at 64-82 us with every counter < 25% -- the common factor was the
// barrier-coupled LDS staging. But the LDS tier here transports NO cross-lane
// data: the DMA wrote lane l's bytes from a global address computed with lane
// l's own (l15,quad), and the fragment read returned lane l's own slot. Both
// A and B MFMA fragments are CONTIGUOUS 16B per lane in global memory (xh
// row-major, BT j-major). So fragments are loaded directly to registers with
// plain global_load_dwordx4: no LDS, no s_barrier, no vmcnt asm, no inter-
// wave coupling. Compiler is free to software-pipeline all 16 stages; each
// wave hides its own latency with ~12 loads in flight.
//
// B (BT, 393 KB) is re-read per block from L2 (fits each XCD's 4 MB; ~300 MB
// aggregate L2 traffic = ~9 us at 34 TB/s). A read once (xh panel reused
// in-register for the -deg fold; stages 8..15 read Gh).
//   out = x@Wself - (deg o x)@Wdst + G@Wsrc + bself + deg*(bsrc-bdst)
// BM=64 x BN=256 (full width), grid 782, 4 waves; per-wave 64x64 output:
// acc = 4x4 floatx4 = 64 VGPR, ~150 total, launch_bounds(256,2) (round-1
// lesson: acc must fit the budget; round-5 lesson: keep >=2 blocks/CU).
// ---------------------------------------------------------------------------
__global__ __launch_bounds__(256, 2) void mfma_gemm(
    const ushort_t* __restrict__ xh, const ushort_t* __restrict__ Gh,
    const ushort_t* __restrict__ BT, const int* __restrict__ deg,
    const float* __restrict__ bsrc, const float* __restrict__ bdst,
    const float* __restrict__ bself, float* __restrict__ out, int N)
{
    const int tid = threadIdx.x;
    const int lane = tid & 63, wave = tid >> 6;
    const int quad = lane >> 4, l15 = lane & 15;
    const int mbase = blockIdx.x * 64;

    // A fragment addresses + -deg row scales; all 4 waves read the same
    // 64 A-rows (L2 broadcast), each owns a disjoint 64-col slice of B/out.
    size_t aoff[4];
    float negdeg[4];
    #pragma unroll
    for (int im = 0; im < 4; ++im) {
        int r = mbase + im * 16 + l15;
        if (r >= N) r = N - 1;
        aoff[im] = (size_t)r * 256 + (size_t)(quad * 8);
        negdeg[im] = -(float)deg[r];
    }

    // per-lane B fragment base pointers (j-major BT: 16B contiguous per lane)
    const ushort_t* bp[4];
    #pragma unroll
    for (int jn = 0; jn < 4; ++jn)
        bp[jn] = BT + (size_t)(wave * 64 + jn * 16 + l15) * 768 + quad * 8;

    floatx4 acc[4][4] = {};

    #pragma unroll
    for (int s = 0; s < 16; ++s) {
        const ushort_t* Ap = (s < 8) ? xh : Gh;
        const int ka = (s & 7) * 32;

        short8 af[4];
        #pragma unroll
        for (int im = 0; im < 4; ++im)
            af[im] = *(const short8*)(Ap + aoff[im] + ka);

        if (s < 8) {
            const int kb = s * 32;            // Wself chunk
            short8 bfs[4], bfd[4];
            #pragma unroll
            for (int jn = 0; jn < 4; ++jn)
                bfs[jn] = *(const short8*)(bp[jn] + kb);
            #pragma unroll
            for (int jn = 0; jn < 4; ++jn)
                bfd[jn] = *(const short8*)(bp[jn] + 512 + kb);   // Wdst chunk

            #pragma unroll
            for (int jn = 0; jn < 4; ++jn)
                #pragma unroll
                for (int im = 0; im < 4; ++im)
                    acc[im][jn] = __builtin_amdgcn_mfma_f32_16x16x32_bf16(
                        af[im], bfs[jn], acc[im][jn], 0, 0, 0);

            // -deg fold: reuse the x fragment in-register against Wdst
            short8 afd[4];
            #pragma unroll
            for (int im = 0; im < 4; ++im) {
                short8 t = af[im];
                #pragma unroll
                for (int j = 0; j < 8; ++j) {
                    float f = bf2f((ushort_t)t[j]) * negdeg[im];
                    t[j] = (short)f2bf(f);
                }
                afd[im] = t;
            }
            #pragma unroll
            for (int jn = 0; jn < 4; ++jn)
                #pragma unroll
                for (int im = 0; im < 4; ++im)
                    acc[im][jn] = __builtin_amdgcn_mfma_f32_16x16x32_bf16(
                        afd[im], bfd[jn], acc[im][jn], 0, 0, 0);
        } else {
            const int kb = 256 + (s - 8) * 32;   // Wsrc chunk
            short8 bfs[4];
            #pragma unroll
            for (int jn = 0; jn < 4; ++jn)
                bfs[jn] = *(const short8*)(bp[jn] + kb);
            #pragma unroll
            for (int jn = 0; jn < 4; ++jn)
                #pragma unroll
                for (int im = 0; im < 4; ++im)
                    acc[im][jn] = __builtin_amdgcn_mfma_f32_16x16x32_bf16(
                        af[im], bfs[jn], acc[im][jn], 0, 0, 0);
        }
    }

    // deg for the 16 rows this thread writes (bias term)
    float degv[4][4];
    #pragma unroll
    for (int im = 0; im < 4; ++im)
        #pragma unroll
        for (int r = 0; r < 4; ++r) {
            int gm = mbase + im * 16 + quad * 4 + r;
            degv[im][r] = (gm < N) ? (float)deg[gm] : 0.f;
        }

    // C/D layout: col = lane&15, row = quad*4 + reg
    #pragma unroll
    for (int jn = 0; jn < 4; ++jn) {
        int gn = wave * 64 + jn * 16 + l15;
        float bs = bself[gn];
        float db = bsrc[gn] - bdst[gn];
        #pragma unroll
        for (int im = 0; im < 4; ++im) {
            #pragma unroll
            for (int r = 0; r < 4; ++r) {
                int gm = mbase + im * 16 + quad * 4 + r;
                if (gm < N) {
                    out[(size_t)gm * 256 + gn] =
                        acc[im][jn][r] + bs + degv[im][r] * db;
                }
            }
        }
    }
}

extern "C" void kernel_launch(void* const* d_in, const int* in_sizes, int n_in,
                              void* d_out, int out_size, void* d_ws, size_t ws_size,
                              hipStream_t stream) {
    const float* x     = (const float*)d_in[0];
    const int*   eidx  = (const int*)d_in[1];
    const float* Wsrc  = (const float*)d_in[2];
    const float* bsrc  = (const float*)d_in[3];
    const float* Wdst  = (const float*)d_in[4];
    const float* bdst  = (const float*)d_in[5];
    const float* Wself = (const float*)d_in[6];
    const float* bself = (const float*)d_in[7];
    float* out = (float*)d_out;

    const int N = in_sizes[0] / D;       // 50000
    const int E = in_sizes[1] / 2;       // 800000
    const int* row = eidx;
    const int* col = eidx + E;

    // ws layout: xh | Gh | BT | deg | off | partials | bucket
    // rank[] (E ints) is ALIASED onto Gh: dead before segsum writes Gh.
    char* p = (char*)d_ws;
    ushort_t* xh  = (ushort_t*)p;        p += (size_t)N * D * sizeof(ushort_t);
    ushort_t* Gh  = (ushort_t*)p;        int* rank = (int*)p;
                                         p += (size_t)N * D * sizeof(ushort_t);
    ushort_t* BT  = (ushort_t*)p;        p += (size_t)768 * 256 * sizeof(ushort_t);
    int* deg      = (int*)p;             p += (size_t)N * sizeof(int);
    int* off      = (int*)p;             p += (size_t)N * sizeof(int);
    int* partials = (int*)p;             p += 64 * sizeof(int);
    int* bucket   = (int*)p;

    hipMemsetAsync(deg, 0, (size_t)N * sizeof(int), stream);

    const int total8 = N * D / 8;                 // 1,600,000
    const int degB = (E + 255) / 256;             // 3125
    const int cvtB = (total8 + 255) / 256;        // 6250
    const int btB  = (256 * 768 + 255) / 256;     // 768
    prep_kernel<<<degB + cvtB + btB, 256, 0, stream>>>(col, deg, rank, x, xh,
                                                       Wself, Wsrc, Wdst, BT,
                                                       E, total8, degB, cvtB);
    const int n4 = N / 4;                         // 12500
    const int nblk = (n4 + 255) / 256;            // 49 (<= 64 required by scanC)
    scanA<<<nblk, 256, 0, stream>>>(deg, off, partials, n4);
    scanC<<<nblk, 256, 0, stream>>>(off, partials, n4);
    fill_kernel<<<(E + 255) / 256, 256, 0, stream>>>(row, col, rank, off, bucket, E);
    segsum_kernel<<<(N + 3) / 4, 256, 0, stream>>>(xh, off, deg, bucket, Gh, N);

    mfma_gemm<<<(N + 63) / 64, 256, 0, stream>>>(xh, Gh, BT, deg,
                                                 bsrc, bdst, bself, out, N);
}

// Round 7
// 302.630 us; speedup vs baseline: 1.0162x; 1.0162x over previous
//
#include <hip/hip_runtime.h>

#define D 256

typedef unsigned short ushort_t;
typedef unsigned int uint_t;
typedef __attribute__((ext_vector_type(8))) short short8;
typedef __attribute__((ext_vector_type(4))) float floatx4;

static __device__ __forceinline__ ushort_t f2bf(float f) {
    union { float f; uint_t u; } c; c.f = f;
    uint_t r = (c.u + 0x7FFFu + ((c.u >> 16) & 1u)) >> 16;   // RN-even
    return (ushort_t)r;
}
static __device__ __forceinline__ float bf2f(ushort_t b) {
    union { uint_t u; float f; } c; c.u = ((uint_t)b) << 16;
    return c.f;
}

// async global->LDS DMA, 16B per lane, dest = uniform base + lane*16
static __device__ __forceinline__ void async16(const void* g, void* l) {
    __builtin_amdgcn_global_load_lds(
        (const __attribute__((address_space(1))) void*)g,
        (__attribute__((address_space(3))) void*)l, 16, 0, 0);
}

// ---------------------------------------------------------------------------
// Fused prep, 3 grid sections:
//  [0,degB):      rank[e] = atomicAdd(&deg[col[e]],1)  (histogram + edge rank)
//  [degB,+cvtB):  x -> bf16 (xh)
//  rest:          BT[j][k] j-major: k<256 Wself[k][j] | k<512 Wsrc | k<768 Wdst
// ---------------------------------------------------------------------------
__global__ void prep_kernel(const int* __restrict__ col, int* __restrict__ deg,
                            int* __restrict__ rank,
                            const float* __restrict__ x, ushort_t* __restrict__ xh,
                            const float* __restrict__ Wself, const float* __restrict__ Wsrc,
                            const float* __restrict__ Wdst, ushort_t* __restrict__ BT,
                            int E, int total8, int degB, int cvtB) {
    int b = blockIdx.x;
    if (b < degB) {
        int e = b * 256 + threadIdx.x;
        if (e < E) rank[e] = atomicAdd(&deg[col[e]], 1);
    } else if (b < degB + cvtB) {
        int i = (b - degB) * 256 + threadIdx.x;
        if (i >= total8) return;
        float4 a = ((const float4*)x)[i * 2];
        float4 bb = ((const float4*)x)[i * 2 + 1];
        uint4 o;
        o.x = f2bf(a.x) | ((uint_t)f2bf(a.y) << 16);
        o.y = f2bf(a.z) | ((uint_t)f2bf(a.w) << 16);
        o.z = f2bf(bb.x) | ((uint_t)f2bf(bb.y) << 16);
        o.w = f2bf(bb.z) | ((uint_t)f2bf(bb.w) << 16);
        ((uint4*)xh)[i] = o;
    } else {
        int id = (b - degB - cvtB) * 256 + threadIdx.x;   // j*768+k
        if (id >= 256 * 768) return;
        int j = id / 768, k = id % 768;
        float v;
        if (k < 256)      v = Wself[(size_t)k * 256 + j];
        else if (k < 512) v = Wsrc [(size_t)(k - 256) * 256 + j];
        else              v = Wdst [(size_t)(k - 512) * 256 + j];
        BT[id] = f2bf(v);
    }
}

// ---------------------------------------------------------------------------
// Scan phase A: per-block (1024 elems) local exclusive scan into off,
// block totals into partials. 256 threads x int4.
// ---------------------------------------------------------------------------
__global__ __launch_bounds__(256) void scanA(const int* __restrict__ deg,
                                             int* __restrict__ off,
                                             int* __restrict__ partials, int n4) {
    __shared__ int wtot[4];
    const int tid = threadIdx.x, lane = tid & 63, wid = tid >> 6;
    int i4 = blockIdx.x * 256 + tid;
    int4 v = (i4 < n4) ? ((const int4*)deg)[i4] : make_int4(0, 0, 0, 0);
    int s = v.x + v.y + v.z + v.w;
    int incl = s;
    #pragma unroll
    for (int st = 1; st < 64; st <<= 1) {
        int t = __shfl_up(incl, st, 64);
        if (lane >= st) incl += t;
    }
    if (lane == 63) wtot[wid] = incl;
    __syncthreads();
    int wbase = 0;
    #pragma unroll
    for (int w = 0; w < 4; ++w) if (w < wid) wbase += wtot[w];
    int excl = incl - s + wbase;
    if (i4 < n4) {
        int4 o;
        o.x = excl; o.y = o.x + v.x; o.z = o.y + v.y; o.w = o.z + v.z;
        ((int4*)off)[i4] = o;
    }
    if (tid == 0) partials[blockIdx.x] = wtot[0] + wtot[1] + wtot[2] + wtot[3];
}

// ---------------------------------------------------------------------------
// Scan phase C: add exclusive block base (sum of earlier partials, <=64 blocks).
// ---------------------------------------------------------------------------
__global__ __launch_bounds__(256) void scanC(int* __restrict__ off,
                                             const int* __restrict__ partials, int n4) {
    __shared__ int base_s;
    const int tid = threadIdx.x;
    if (tid < 64) {
        int v = (tid < blockIdx.x) ? partials[tid] : 0;
        #pragma unroll
        for (int st = 32; st; st >>= 1) v += __shfl_down(v, st, 64);
        if (tid == 0) base_s = v;
    }
    __syncthreads();
    int base = base_s;
    int i4 = blockIdx.x * 256 + tid;
    if (i4 < n4) {
        int4 o = ((int4*)off)[i4];
        o.x += base; o.y += base; o.z += base; o.w += base;
        ((int4*)off)[i4] = o;
    }
}

// ---------------------------------------------------------------------------
// Atomic-free bucket fill using precomputed ranks.
// ---------------------------------------------------------------------------
__global__ void fill_kernel(const int* __restrict__ row, const int* __restrict__ col,
                            const int* __restrict__ rank, const int* __restrict__ off,
                            int* __restrict__ bucket, int E) {
    int e = blockIdx.x * blockDim.x + threadIdx.x;
    if (e >= E) return;
    bucket[off[col[e]] + rank[e]] = row[e];
}

// ---------------------------------------------------------------------------
// segsum v2: persistent grid-stride waves, 2 rows per wave.
//  * lanes 0-31 process even rows, lanes 32-63 odd rows of each pair;
//    16 B/lane (short8) -> one 512 B fully-coalesced transaction per row.
//  * 8 rows in flight per main-loop iter (4 pairs) = 2x the MLP of v1.
//  * grid-stride over nodes (512 blocks x 4 waves): ~24 nodes/wave averages
//    out Poisson(16) degree imbalance (v1: block lifetime = max of 4 draws),
//    and kills 12.5K-tiny-block launch/drain overhead.
//  * halves combined with one shfl_xor(32) pass; lanes 0-31 store 16 B.
// ---------------------------------------------------------------------------
__global__ __launch_bounds__(256) void segsum_kernel(const ushort_t* __restrict__ xh,
                                                     const int* __restrict__ off,
                                                     const int* __restrict__ deg,
                                                     const int* __restrict__ bucket,
                                                     ushort_t* __restrict__ Gh,
                                                     int N, int nwaves) {
    const int gwid = blockIdx.x * 4 + (threadIdx.x >> 6);
    const int lane = threadIdx.x & 63;
    const int half = lane >> 5;              // 0: even row of pair, 1: odd row
    const size_t eoff = (size_t)(lane & 31) * 8;   // element offset (16 B/lane)

    for (int node = gwid; node < N; node += nwaves) {
        const int start = off[node];
        const int cnt = deg[node];
        float a[8] = {0.f, 0.f, 0.f, 0.f, 0.f, 0.f, 0.f, 0.f};
        int i = 0;
        for (; i + 8 <= cnt; i += 8) {
            int r0 = bucket[start + i + 0 + half];
            int r1 = bucket[start + i + 2 + half];
            int r2 = bucket[start + i + 4 + half];
            int r3 = bucket[start + i + 6 + half];
            short8 v0 = *(const short8*)(xh + (size_t)r0 * D + eoff);
            short8 v1 = *(const short8*)(xh + (size_t)r1 * D + eoff);
            short8 v2 = *(const short8*)(xh + (size_t)r2 * D + eoff);
            short8 v3 = *(const short8*)(xh + (size_t)r3 * D + eoff);
            #pragma unroll
            for (int j = 0; j < 8; ++j)
                a[j] += (bf2f((ushort_t)v0[j]) + bf2f((ushort_t)v1[j])) +
                        (bf2f((ushort_t)v2[j]) + bf2f((ushort_t)v3[j]));
        }
        for (; i + 2 <= cnt; i += 2) {
            int r = bucket[start + i + half];
            short8 v = *(const short8*)(xh + (size_t)r * D + eoff);
            #pragma unroll
            for (int j = 0; j < 8; ++j) a[j] += bf2f((ushort_t)v[j]);
        }
        if (i < cnt && half == 0) {          // odd leftover row: even-half only
            int r = bucket[start + i];
            short8 v = *(const short8*)(xh + (size_t)r * D + eoff);
            #pragma unroll
            for (int j = 0; j < 8; ++j) a[j] += bf2f((ushort_t)v[j]);
        }
        // combine the two halves (all lanes participate; no divergence here)
        #pragma unroll
        for (int j = 0; j < 8; ++j) a[j] += __shfl_xor(a[j], 32, 64);
        if (half == 0) {
            short8 o;
            #pragma unroll
            for (int j = 0; j < 8; ++j) o[j] = (short)f2bf(a[j]);
            *(short8*)(Gh + (size_t)node * D + eoff) = o;
        }
    }
}

// ---------------------------------------------------------------------------
// bf16 MFMA GEMM, fragment-major LDS + global_load_lds (zero bank conflicts).
// ROUND-0 VERSION VERBATIM -- best measured (63.9-65.2 us). Rounds 1-6 tried:
// (256,3) occupancy bump -> 64-reg spill, 98 us; 2-phase dbuf -> neutral;
// 64x128 single-acc -> 84 us; 3-buf counted-vmcnt ring -> neutral; reg-A +
// DMA-B 391-block -> 82 us; zero-LDS register-direct -> 99 us. Conclusion:
// at 2 blocks/CU the implicit wave-level overlap already captures what
// source-level pipelining would add (guide m114); DO NOT touch the schedule.
//   kt 0..7 : A=xh tile; acc1 += A@Wself-tile, acc2 += A@Wdst-tile (A reused)
//   kt 8..15: A=Gh tile; acc1 += A@Wsrc-tile
//   out = acc1 - deg*acc2 + bself + deg*(bsrc-bdst)
// ---------------------------------------------------------------------------
__global__ __launch_bounds__(256, 2) void mfma_gemm(
    const ushort_t* __restrict__ xh, const ushort_t* __restrict__ Gh,
    const ushort_t* __restrict__ BT, const int* __restrict__ deg,
    const float* __restrict__ bsrc, const float* __restrict__ bdst,
    const float* __restrict__ bself, float* __restrict__ out, int N)
{
    __shared__ ushort_t As[8][64][8];   // 8 KB
    __shared__ ushort_t Bs[8][64][8];   // 8 KB
    __shared__ ushort_t Ds[8][64][8];   // 8 KB (Wdst tiles, kt<8)

    const int tid = threadIdx.x;
    const int lane = tid & 63, wave = tid >> 6;
    const int quad = lane >> 4, l15 = lane & 15;
    const int mg = (wave >> 1) * 4, ng = (wave & 1) * 4;   // fragment group bases
    const int mbase = blockIdx.x * 128, nbase = blockIdx.y * 128;

    // this wave stages groups ga0, ga1 of each tile
    const int ga0 = wave * 2, ga1 = ga0 + 1;
    int ar0 = mbase + ga0 * 16 + l15; if (ar0 >= N) ar0 = N - 1;
    int ar1 = mbase + ga1 * 16 + l15; if (ar1 >= N) ar1 = N - 1;
    const size_t aoff0 = (size_t)ar0 * 256 + quad * 8;
    const size_t aoff1 = (size_t)ar1 * 256 + quad * 8;
    const ushort_t* bp0 = BT + (size_t)(nbase + ga0 * 16 + l15) * 768 + quad * 8;
    const ushort_t* bp1 = BT + (size_t)(nbase + ga1 * 16 + l15) * 768 + quad * 8;

    floatx4 acc1[4][4] = {};
    floatx4 acc2[4][4] = {};

    for (int kt = 0; kt < 16; ++kt) {
        const ushort_t* Asrc = (kt < 8) ? xh : Gh;
        const int ka = (kt & 7) * 32;      // k-col within A source
        const int kb = kt * 32;            // k-col within BT (Wself then Wsrc)
        async16(Asrc + aoff0 + ka, &As[ga0][0][0]);
        async16(Asrc + aoff1 + ka, &As[ga1][0][0]);
        async16(bp0 + kb, &Bs[ga0][0][0]);
        async16(bp1 + kb, &Bs[ga1][0][0]);
        if (kt < 8) {
            async16(bp0 + 512 + kb, &Ds[ga0][0][0]);
            async16(bp1 + 512 + kb, &Ds[ga1][0][0]);
        }
        __syncthreads();

        short8 af[4], bfr[4];
        #pragma unroll
        for (int im = 0; im < 4; ++im)
            af[im] = *(const short8*)(&As[mg + im][lane][0]);
        #pragma unroll
        for (int in = 0; in < 4; ++in)
            bfr[in] = *(const short8*)(&Bs[ng + in][lane][0]);
        #pragma unroll
        for (int im = 0; im < 4; ++im)
            #pragma unroll
            for (int in = 0; in < 4; ++in)
                acc1[im][in] = __builtin_amdgcn_mfma_f32_16x16x32_bf16(
                    af[im], bfr[in], acc1[im][in], 0, 0, 0);
        if (kt < 8) {
            short8 df[4];
            #pragma unroll
            for (int in = 0; in < 4; ++in)
                df[in] = *(const short8*)(&Ds[ng + in][lane][0]);
            #pragma unroll
            for (int im = 0; im < 4; ++im)
                #pragma unroll
                for (int in = 0; in < 4; ++in)
                    acc2[im][in] = __builtin_amdgcn_mfma_f32_16x16x32_bf16(
                        af[im], df[in], acc2[im][in], 0, 0, 0);
        }
        __syncthreads();
    }

    // hoist deg for the 16 rows this thread writes
    float degv[4][4];
    #pragma unroll
    for (int im = 0; im < 4; ++im)
        #pragma unroll
        for (int r = 0; r < 4; ++r) {
            int gm = mbase + (wave >> 1) * 64 + im * 16 + quad * 4 + r;
            degv[im][r] = (gm < N) ? (float)deg[gm] : 0.f;
        }

    // C/D layout: col = lane&15, row = quad*4 + reg
    #pragma unroll
    for (int in = 0; in < 4; ++in) {
        int gn = nbase + (wave & 1) * 64 + in * 16 + l15;
        float bs = bself[gn];
        float db = bsrc[gn] - bdst[gn];
        #pragma unroll
        for (int im = 0; im < 4; ++im) {
            #pragma unroll
            for (int r = 0; r < 4; ++r) {
                int gm = mbase + (wave >> 1) * 64 + im * 16 + quad * 4 + r;
                if (gm < N) {
                    float d = degv[im][r];
                    out[(size_t)gm * 256 + gn] =
                        acc1[im][in][r] - d * acc2[im][in][r] + bs + d * db;
                }
            }
        }
    }
}

extern "C" void kernel_launch(void* const* d_in, const int* in_sizes, int n_in,
                              void* d_out, int out_size, void* d_ws, size_t ws_size,
                              hipStream_t stream) {
    const float* x     = (const float*)d_in[0];
    const int*   eidx  = (const int*)d_in[1];
    const float* Wsrc  = (const float*)d_in[2];
    const float* bsrc  = (const float*)d_in[3];
    const float* Wdst  = (const float*)d_in[4];
    const float* bdst  = (const float*)d_in[5];
    const float* Wself = (const float*)d_in[6];
    const float* bself = (const float*)d_in[7];
    float* out = (float*)d_out;

    const int N = in_sizes[0] / D;       // 50000
    const int E = in_sizes[1] / 2;       // 800000
    const int* row = eidx;
    const int* col = eidx + E;

    // ws layout: xh | Gh | BT | deg | off | partials | bucket
    // rank[] (E ints) is ALIASED onto Gh: dead before segsum writes Gh.
    char* p = (char*)d_ws;
    ushort_t* xh  = (ushort_t*)p;        p += (size_t)N * D * sizeof(ushort_t);
    ushort_t* Gh  = (ushort_t*)p;        int* rank = (int*)p;
                                         p += (size_t)N * D * sizeof(ushort_t);
    ushort_t* BT  = (ushort_t*)p;        p += (size_t)768 * 256 * sizeof(ushort_t);
    int* deg      = (int*)p;             p += (size_t)N * sizeof(int);
    int* off      = (int*)p;             p += (size_t)N * sizeof(int);
    int* partials = (int*)p;             p += 64 * sizeof(int);
    int* bucket   = (int*)p;

    hipMemsetAsync(deg, 0, (size_t)N * sizeof(int), stream);

    const int total8 = N * D / 8;                 // 1,600,000
    const int degB = (E + 255) / 256;             // 3125
    const int cvtB = (total8 + 255) / 256;        // 6250
    const int btB  = (256 * 768 + 255) / 256;     // 768
    prep_kernel<<<degB + cvtB + btB, 256, 0, stream>>>(col, deg, rank, x, xh,
                                                       Wself, Wsrc, Wdst, BT,
                                                       E, total8, degB, cvtB);
    const int n4 = N / 4;                         // 12500
    const int nblk = (n4 + 255) / 256;            // 49 (<= 64 required by scanC)
    scanA<<<nblk, 256, 0, stream>>>(deg, off, partials, n4);
    scanC<<<nblk, 256, 0, stream>>>(off, partials, n4);
    fill_kernel<<<(E + 255) / 256, 256, 0, stream>>>(row, col, rank, off, bucket, E);

    const int sblocks = 512;                      // persistent: ~24 nodes/wave
    segsum_kernel<<<sblocks, 256, 0, stream>>>(xh, off, deg, bucket, Gh, N,
                                               sblocks * 4);

    dim3 grid((N + 127) / 128, 2);
    mfma_gemm<<<grid, 256, 0, stream>>>(xh, Gh, BT, deg, bsrc, bdst, bself, out, N);
}

// Round 8
// 278.644 us; speedup vs baseline: 1.1037x; 1.0861x over previous
//
#include <hip/hip_runtime.h>

#define D 256

typedef unsigned short ushort_t;
typedef unsigned int uint_t;
typedef __attribute__((ext_vector_type(8))) short short8;
typedef __attribute__((ext_vector_type(4))) float floatx4;

static __device__ __forceinline__ ushort_t f2bf(float f) {
    union { float f; uint_t u; } c; c.f = f;
    uint_t r = (c.u + 0x7FFFu + ((c.u >> 16) & 1u)) >> 16;   // RN-even
    return (ushort_t)r;
}
static __device__ __forceinline__ float bf2f(ushort_t b) {
    union { uint_t u; float f; } c; c.u = ((uint_t)b) << 16;
    return c.f;
}

// async global->LDS DMA, 16B per lane, dest = uniform base + lane*16
static __device__ __forceinline__ void async16(const void* g, void* l) {
    __builtin_amdgcn_global_load_lds(
        (const __attribute__((address_space(1))) void*)g,
        (__attribute__((address_space(3))) void*)l, 16, 0, 0);
}

// ---------------------------------------------------------------------------
// Fused prep, 3 grid sections:
//  [0,degB):      rank[e] = atomicAdd(&deg[col[e]],1)  (histogram + edge rank)
//  [degB,+cvtB):  x -> bf16 (xh)
//  rest:          BT[j][k] j-major: k<256 Wself[k][j] | k<512 Wsrc | k<768 Wdst
// ---------------------------------------------------------------------------
__global__ void prep_kernel(const int* __restrict__ col, int* __restrict__ deg,
                            int* __restrict__ rank,
                            const float* __restrict__ x, ushort_t* __restrict__ xh,
                            const float* __restrict__ Wself, const float* __restrict__ Wsrc,
                            const float* __restrict__ Wdst, ushort_t* __restrict__ BT,
                            int E, int total8, int degB, int cvtB) {
    int b = blockIdx.x;
    if (b < degB) {
        int e = b * 256 + threadIdx.x;
        if (e < E) rank[e] = atomicAdd(&deg[col[e]], 1);
    } else if (b < degB + cvtB) {
        int i = (b - degB) * 256 + threadIdx.x;
        if (i >= total8) return;
        float4 a = ((const float4*)x)[i * 2];
        float4 bb = ((const float4*)x)[i * 2 + 1];
        uint4 o;
        o.x = f2bf(a.x) | ((uint_t)f2bf(a.y) << 16);
        o.y = f2bf(a.z) | ((uint_t)f2bf(a.w) << 16);
        o.z = f2bf(bb.x) | ((uint_t)f2bf(bb.y) << 16);
        o.w = f2bf(bb.z) | ((uint_t)f2bf(bb.w) << 16);
        ((uint4*)xh)[i] = o;
    } else {
        int id = (b - degB - cvtB) * 256 + threadIdx.x;   // j*768+k
        if (id >= 256 * 768) return;
        int j = id / 768, k = id % 768;
        float v;
        if (k < 256)      v = Wself[(size_t)k * 256 + j];
        else if (k < 512) v = Wsrc [(size_t)(k - 256) * 256 + j];
        else              v = Wdst [(size_t)(k - 512) * 256 + j];
        BT[id] = f2bf(v);
    }
}

// ---------------------------------------------------------------------------
// Scan phase A: per-block (1024 elems) local exclusive scan into off,
// block totals into partials. 256 threads x int4.
// ---------------------------------------------------------------------------
__global__ __launch_bounds__(256) void scanA(const int* __restrict__ deg,
                                             int* __restrict__ off,
                                             int* __restrict__ partials, int n4) {
    __shared__ int wtot[4];
    const int tid = threadIdx.x, lane = tid & 63, wid = tid >> 6;
    int i4 = blockIdx.x * 256 + tid;
    int4 v = (i4 < n4) ? ((const int4*)deg)[i4] : make_int4(0, 0, 0, 0);
    int s = v.x + v.y + v.z + v.w;
    int incl = s;
    #pragma unroll
    for (int st = 1; st < 64; st <<= 1) {
        int t = __shfl_up(incl, st, 64);
        if (lane >= st) incl += t;
    }
    if (lane == 63) wtot[wid] = incl;
    __syncthreads();
    int wbase = 0;
    #pragma unroll
    for (int w = 0; w < 4; ++w) if (w < wid) wbase += wtot[w];
    int excl = incl - s + wbase;
    if (i4 < n4) {
        int4 o;
        o.x = excl; o.y = o.x + v.x; o.z = o.y + v.y; o.w = o.z + v.z;
        ((int4*)off)[i4] = o;
    }
    if (tid == 0) partials[blockIdx.x] = wtot[0] + wtot[1] + wtot[2] + wtot[3];
}

// ---------------------------------------------------------------------------
// Scan phase C: add exclusive block base (sum of earlier partials, <=64 blocks).
// ---------------------------------------------------------------------------
__global__ __launch_bounds__(256) void scanC(int* __restrict__ off,
                                             const int* __restrict__ partials, int n4) {
    __shared__ int base_s;
    const int tid = threadIdx.x;
    if (tid < 64) {
        int v = (tid < blockIdx.x) ? partials[tid] : 0;
        #pragma unroll
        for (int st = 32; st; st >>= 1) v += __shfl_down(v, st, 64);
        if (tid == 0) base_s = v;
    }
    __syncthreads();
    int base = base_s;
    int i4 = blockIdx.x * 256 + tid;
    if (i4 < n4) {
        int4 o = ((int4*)off)[i4];
        o.x += base; o.y += base; o.z += base; o.w += base;
        ((int4*)off)[i4] = o;
    }
}

// ---------------------------------------------------------------------------
// Atomic-free bucket fill using precomputed ranks.
// ---------------------------------------------------------------------------
__global__ void fill_kernel(const int* __restrict__ row, const int* __restrict__ col,
                            const int* __restrict__ rank, const int* __restrict__ off,
                            int* __restrict__ bucket, int E) {
    int e = blockIdx.x * blockDim.x + threadIdx.x;
    if (e >= E) return;
    bucket[off[col[e]] + rank[e]] = row[e];
}

// ---------------------------------------------------------------------------
// segsum v3: v2 wave structure, FULL-MACHINE occupancy.
// Round-7 lesson: 512 blocks = 2 waves/SIMD strangled a latency-bound gather
// (Occupancy 19%, 2.4 TB/s, 85 us -- slower than the naive v1). TLP is the
// only latency-hiding mechanism here (VALU 20%, no LDS, no MFMA).
// 2048 blocks x 4 waves = 8192 waves = 8 waves/SIMD (HW max at VGPR=32,
// LDS=0, 256-thread blocks); ~6 nodes/wave grid-stride still averages
// Poisson(16) degree imbalance.
//  * lanes 0-31 even row / 32-63 odd row of each pair; 16 B/lane short8
//    -> one 512 B fully-coalesced transaction per row; 8 rows in flight.
//  * halves combined with one shfl_xor(32); lanes 0-31 store 16 B.
// ---------------------------------------------------------------------------
__global__ __launch_bounds__(256) void segsum_kernel(const ushort_t* __restrict__ xh,
                                                     const int* __restrict__ off,
                                                     const int* __restrict__ deg,
                                                     const int* __restrict__ bucket,
                                                     ushort_t* __restrict__ Gh,
                                                     int N, int nwaves) {
    const int gwid = blockIdx.x * 4 + (threadIdx.x >> 6);
    const int lane = threadIdx.x & 63;
    const int half = lane >> 5;              // 0: even row of pair, 1: odd row
    const size_t eoff = (size_t)(lane & 31) * 8;   // element offset (16 B/lane)

    for (int node = gwid; node < N; node += nwaves) {
        const int start = off[node];
        const int cnt = deg[node];
        float a[8] = {0.f, 0.f, 0.f, 0.f, 0.f, 0.f, 0.f, 0.f};
        int i = 0;
        for (; i + 8 <= cnt; i += 8) {
            int r0 = bucket[start + i + 0 + half];
            int r1 = bucket[start + i + 2 + half];
            int r2 = bucket[start + i + 4 + half];
            int r3 = bucket[start + i + 6 + half];
            short8 v0 = *(const short8*)(xh + (size_t)r0 * D + eoff);
            short8 v1 = *(const short8*)(xh + (size_t)r1 * D + eoff);
            short8 v2 = *(const short8*)(xh + (size_t)r2 * D + eoff);
            short8 v3 = *(const short8*)(xh + (size_t)r3 * D + eoff);
            #pragma unroll
            for (int j = 0; j < 8; ++j)
                a[j] += (bf2f((ushort_t)v0[j]) + bf2f((ushort_t)v1[j])) +
                        (bf2f((ushort_t)v2[j]) + bf2f((ushort_t)v3[j]));
        }
        for (; i + 2 <= cnt; i += 2) {
            int r = bucket[start + i + half];
            short8 v = *(const short8*)(xh + (size_t)r * D + eoff);
            #pragma unroll
            for (int j = 0; j < 8; ++j) a[j] += bf2f((ushort_t)v[j]);
        }
        if (i < cnt && half == 0) {          // odd leftover row: even-half only
            int r = bucket[start + i];
            short8 v = *(const short8*)(xh + (size_t)r * D + eoff);
            #pragma unroll
            for (int j = 0; j < 8; ++j) a[j] += bf2f((ushort_t)v[j]);
        }
        // combine the two halves (all lanes participate; no divergence here)
        #pragma unroll
        for (int j = 0; j < 8; ++j) a[j] += __shfl_xor(a[j], 32, 64);
        if (half == 0) {
            short8 o;
            #pragma unroll
            for (int j = 0; j < 8; ++j) o[j] = (short)f2bf(a[j]);
            *(short8*)(Gh + (size_t)node * D + eoff) = o;
        }
    }
}

// ---------------------------------------------------------------------------
// bf16 MFMA GEMM, fragment-major LDS + global_load_lds (zero bank conflicts).
// ROUND-0 VERSION VERBATIM -- best measured (63.9-65.2 us). Rounds 1-6 tried:
// (256,3) occupancy bump -> 64-reg spill, 98 us; 2-phase dbuf -> neutral;
// 64x128 single-acc -> 84 us; 3-buf counted-vmcnt ring -> neutral; reg-A +
// DMA-B 391-block -> 82 us; zero-LDS register-direct -> 99 us. Conclusion:
// at 2 blocks/CU the implicit wave-level overlap already captures what
// source-level pipelining would add (guide m114); DO NOT touch the schedule.
//   kt 0..7 : A=xh tile; acc1 += A@Wself-tile, acc2 += A@Wdst-tile (A reused)
//   kt 8..15: A=Gh tile; acc1 += A@Wsrc-tile
//   out = acc1 - deg*acc2 + bself + deg*(bsrc-bdst)
// ---------------------------------------------------------------------------
__global__ __launch_bounds__(256, 2) void mfma_gemm(
    const ushort_t* __restrict__ xh, const ushort_t* __restrict__ Gh,
    const ushort_t* __restrict__ BT, const int* __restrict__ deg,
    const float* __restrict__ bsrc, const float* __restrict__ bdst,
    const float* __restrict__ bself, float* __restrict__ out, int N)
{
    __shared__ ushort_t As[8][64][8];   // 8 KB
    __shared__ ushort_t Bs[8][64][8];   // 8 KB
    __shared__ ushort_t Ds[8][64][8];   // 8 KB (Wdst tiles, kt<8)

    const int tid = threadIdx.x;
    const int lane = tid & 63, wave = tid >> 6;
    const int quad = lane >> 4, l15 = lane & 15;
    const int mg = (wave >> 1) * 4, ng = (wave & 1) * 4;   // fragment group bases
    const int mbase = blockIdx.x * 128, nbase = blockIdx.y * 128;

    // this wave stages groups ga0, ga1 of each tile
    const int ga0 = wave * 2, ga1 = ga0 + 1;
    int ar0 = mbase + ga0 * 16 + l15; if (ar0 >= N) ar0 = N - 1;
    int ar1 = mbase + ga1 * 16 + l15; if (ar1 >= N) ar1 = N - 1;
    const size_t aoff0 = (size_t)ar0 * 256 + quad * 8;
    const size_t aoff1 = (size_t)ar1 * 256 + quad * 8;
    const ushort_t* bp0 = BT + (size_t)(nbase + ga0 * 16 + l15) * 768 + quad * 8;
    const ushort_t* bp1 = BT + (size_t)(nbase + ga1 * 16 + l15) * 768 + quad * 8;

    floatx4 acc1[4][4] = {};
    floatx4 acc2[4][4] = {};

    for (int kt = 0; kt < 16; ++kt) {
        const ushort_t* Asrc = (kt < 8) ? xh : Gh;
        const int ka = (kt & 7) * 32;      // k-col within A source
        const int kb = kt * 32;            // k-col within BT (Wself then Wsrc)
        async16(Asrc + aoff0 + ka, &As[ga0][0][0]);
        async16(Asrc + aoff1 + ka, &As[ga1][0][0]);
        async16(bp0 + kb, &Bs[ga0][0][0]);
        async16(bp1 + kb, &Bs[ga1][0][0]);
        if (kt < 8) {
            async16(bp0 + 512 + kb, &Ds[ga0][0][0]);
            async16(bp1 + 512 + kb, &Ds[ga1][0][0]);
        }
        __syncthreads();

        short8 af[4], bfr[4];
        #pragma unroll
        for (int im = 0; im < 4; ++im)
            af[im] = *(const short8*)(&As[mg + im][lane][0]);
        #pragma unroll
        for (int in = 0; in < 4; ++in)
            bfr[in] = *(const short8*)(&Bs[ng + in][lane][0]);
        #pragma unroll
        for (int im = 0; im < 4; ++im)
            #pragma unroll
            for (int in = 0; in < 4; ++in)
                acc1[im][in] = __builtin_amdgcn_mfma_f32_16x16x32_bf16(
                    af[im], bfr[in], acc1[im][in], 0, 0, 0);
        if (kt < 8) {
            short8 df[4];
            #pragma unroll
            for (int in = 0; in < 4; ++in)
                df[in] = *(const short8*)(&Ds[ng + in][lane][0]);
            #pragma unroll
            for (int im = 0; im < 4; ++im)
                #pragma unroll
                for (int in = 0; in < 4; ++in)
                    acc2[im][in] = __builtin_amdgcn_mfma_f32_16x16x32_bf16(
                        af[im], df[in], acc2[im][in], 0, 0, 0);
        }
        __syncthreads();
    }

    // hoist deg for the 16 rows this thread writes
    float degv[4][4];
    #pragma unroll
    for (int im = 0; im < 4; ++im)
        #pragma unroll
        for (int r = 0; r < 4; ++r) {
            int gm = mbase + (wave >> 1) * 64 + im * 16 + quad * 4 + r;
            degv[im][r] = (gm < N) ? (float)deg[gm] : 0.f;
        }

    // C/D layout: col = lane&15, row = quad*4 + reg
    #pragma unroll
    for (int in = 0; in < 4; ++in) {
        int gn = nbase + (wave & 1) * 64 + in * 16 + l15;
        float bs = bself[gn];
        float db = bsrc[gn] - bdst[gn];
        #pragma unroll
        for (int im = 0; im < 4; ++im) {
            #pragma unroll
            for (int r = 0; r < 4; ++r) {
                int gm = mbase + (wave >> 1) * 64 + im * 16 + quad * 4 + r;
                if (gm < N) {
                    float d = degv[im][r];
                    out[(size_t)gm * 256 + gn] =
                        acc1[im][in][r] - d * acc2[im][in][r] + bs + d * db;
                }
            }
        }
    }
}

extern "C" void kernel_launch(void* const* d_in, const int* in_sizes, int n_in,
                              void* d_out, int out_size, void* d_ws, size_t ws_size,
                              hipStream_t stream) {
    const float* x     = (const float*)d_in[0];
    const int*   eidx  = (const int*)d_in[1];
    const float* Wsrc  = (const float*)d_in[2];
    const float* bsrc  = (const float*)d_in[3];
    const float* Wdst  = (const float*)d_in[4];
    const float* bdst  = (const float*)d_in[5];
    const float* Wself = (const float*)d_in[6];
    const float* bself = (const float*)d_in[7];
    float* out = (float*)d_out;

    const int N = in_sizes[0] / D;       // 50000
    const int E = in_sizes[1] / 2;       // 800000
    const int* row = eidx;
    const int* col = eidx + E;

    // ws layout: xh | Gh | BT | deg | off | partials | bucket
    // rank[] (E ints) is ALIASED onto Gh: dead before segsum writes Gh.
    char* p = (char*)d_ws;
    ushort_t* xh  = (ushort_t*)p;        p += (size_t)N * D * sizeof(ushort_t);
    ushort_t* Gh  = (ushort_t*)p;        int* rank = (int*)p;
                                         p += (size_t)N * D * sizeof(ushort_t);
    ushort_t* BT  = (ushort_t*)p;        p += (size_t)768 * 256 * sizeof(ushort_t);
    int* deg      = (int*)p;             p += (size_t)N * sizeof(int);
    int* off      = (int*)p;             p += (size_t)N * sizeof(int);
    int* partials = (int*)p;             p += 64 * sizeof(int);
    int* bucket   = (int*)p;

    hipMemsetAsync(deg, 0, (size_t)N * sizeof(int), stream);

    const int total8 = N * D / 8;                 // 1,600,000
    const int degB = (E + 255) / 256;             // 3125
    const int cvtB = (total8 + 255) / 256;        // 6250
    const int btB  = (256 * 768 + 255) / 256;     // 768
    prep_kernel<<<degB + cvtB + btB, 256, 0, stream>>>(col, deg, rank, x, xh,
                                                       Wself, Wsrc, Wdst, BT,
                                                       E, total8, degB, cvtB);
    const int n4 = N / 4;                         // 12500
    const int nblk = (n4 + 255) / 256;            // 49 (<= 64 required by scanC)
    scanA<<<nblk, 256, 0, stream>>>(deg, off, partials, n4);
    scanC<<<nblk, 256, 0, stream>>>(off, partials, n4);
    fill_kernel<<<(E + 255) / 256, 256, 0, stream>>>(row, col, rank, off, bucket, E);

    const int sblocks = 2048;                     // 8 waves/SIMD = HW max TLP
    segsum_kernel<<<sblocks, 256, 0, stream>>>(xh, off, deg, bucket, Gh, N,
                                               sblocks * 4);

    dim3 grid((N + 127) / 128, 2);
    mfma_gemm<<<grid, 256, 0, stream>>>(xh, Gh, BT, deg, bsrc, bdst, bself, out, N);
}